// Round 12
// baseline (408.083 us; speedup 1.0000x reference)
//
#include <hip/hip_runtime.h>

#define N_NODES 100000
#define N_EDGES 3200000
#define IN_CH   384
#define HID     128
#define BKT_SHIFT 7
#define NBKT ((N_NODES + 127) >> 7)      // 782 buckets x 128 dst nodes
#define NTILE 8
#define TILE_SZ 12500                    // src nodes per tile
#define NBINS (NBKT * NTILE)             // 6256 (bucket,tile) cells
#define BINBLK 256                       // blocks in binning passes (full chip)
#define BTHREADS 512
#define CHUNK4 (N_EDGES / 4 / BINBLK)    // 3125 int4 per block (exact)

typedef __attribute__((ext_vector_type(8))) short          bf16x8;
typedef __attribute__((ext_vector_type(8))) unsigned short u16x8;
typedef __attribute__((ext_vector_type(4))) float          f32x4;

static __device__ __forceinline__ unsigned short f2bf(float f) {
    unsigned u = __float_as_uint(f);
    unsigned r = (u + 0x7fffu + ((u >> 16) & 1u)) >> 16;   // RTN-even
    return (unsigned short)r;
}

// ---------------- both W -> transposed bf16: Wt[n][k] ----------------
__global__ void k_wt2(const float* __restrict__ W1, const float* __restrict__ W2,
                      unsigned short* __restrict__ wt1, unsigned short* __restrict__ wt2) {
    int i = blockIdx.x * blockDim.x + threadIdx.x;
    if (i < IN_CH * 128) {
        int k = i >> 7, n = i & 127;
        wt1[(size_t)n * IN_CH + k] = f2bf(W1[i]);
    } else if (i < (IN_CH + HID) * 128) {
        int j = i - IN_CH * 128;
        int k = j >> 7, n = j & 127;
        wt2[(size_t)n * HID + k] = f2bf(W2[j]);
    }
}

// ---------------- pass 1: per-block LDS histogram over (bucket,tile) cells ----------------
__global__ __launch_bounds__(BTHREADS) void k_bhist2(const int* __restrict__ src,
                                                     const int* __restrict__ dst,
                                                     unsigned* __restrict__ hist) {
    __shared__ unsigned lh[NBINS];
    for (int i = threadIdx.x; i < NBINS; i += BTHREADS) lh[i] = 0;
    __syncthreads();
    const int4* s4 = (const int4*)src;
    const int4* d4 = (const int4*)dst;
    const int base = blockIdx.x * CHUNK4;
    for (int i = threadIdx.x; i < CHUNK4; i += BTHREADS) {
        int4 sv = s4[base + i];
        int4 dv = d4[base + i];
        atomicAdd(&lh[(dv.x >> BKT_SHIFT) * NTILE + (unsigned)sv.x / TILE_SZ], 1u);
        atomicAdd(&lh[(dv.y >> BKT_SHIFT) * NTILE + (unsigned)sv.y / TILE_SZ], 1u);
        atomicAdd(&lh[(dv.z >> BKT_SHIFT) * NTILE + (unsigned)sv.z / TILE_SZ], 1u);
        atomicAdd(&lh[(dv.w >> BKT_SHIFT) * NTILE + (unsigned)sv.w / TILE_SZ], 1u);
    }
    __syncthreads();
    for (int i = threadIdx.x; i < NBINS; i += BTHREADS) hist[i * BINBLK + blockIdx.x] = lh[i];
}

// pass 2: per-cell exclusive scan over BINBLK block counts; emit cell totals
__global__ __launch_bounds__(BINBLK) void k_bscan(unsigned* __restrict__ hist,
                                                  unsigned* __restrict__ bintot) {
    __shared__ unsigned s[BINBLK];
    const int b = blockIdx.x, t = threadIdx.x;
    unsigned v = hist[b * BINBLK + t];
    s[t] = v;
    __syncthreads();
    for (int off = 1; off < BINBLK; off <<= 1) {
        unsigned x = s[t];
        unsigned y = (t >= off) ? s[t - off] : 0u;
        __syncthreads();
        s[t] = x + y;
        __syncthreads();
    }
    hist[b * BINBLK + t] = s[t] - v;          // exclusive within cell
    if (t == BINBLK - 1) bintot[b] = s[BINBLK - 1];
}

// pass 3 (merged): single-block exclusive scan of NBINS cell totals -> B2; B2[NBINS] = E
__global__ __launch_bounds__(1024) void k_gs(const unsigned* __restrict__ bintot,
                                             unsigned* __restrict__ B2, int n, int E) {
    __shared__ unsigned s[1024];
    const int t = threadIdx.x;
    const int base = t * 7;                   // 7*1024 = 7168 >= NBINS
    unsigned loc[7];
    unsigned sum = 0;
#pragma unroll
    for (int i = 0; i < 7; i++) {
        unsigned v = (base + i < n) ? bintot[base + i] : 0u;
        loc[i] = sum;
        sum += v;
    }
    s[t] = sum;
    __syncthreads();
    for (int off = 1; off < 1024; off <<= 1) {
        unsigned x = s[t];
        unsigned y = (t >= off) ? s[t - off] : 0u;
        __syncthreads();
        s[t] = x + y;
        __syncthreads();
    }
    unsigned ex = s[t] - sum;
#pragma unroll
    for (int i = 0; i < 7; i++)
        if (base + i < n) B2[base + i] = ex + loc[i];
    if (t == 0) B2[n] = (unsigned)E;
}

// pass 4: scatter packed (loc7|src17) into (bucket,tile)-grouped ebuf; LDS cursors
__global__ __launch_bounds__(BTHREADS) void k_bscat2(const int* __restrict__ src,
                                                     const int* __restrict__ dst,
                                                     const unsigned* __restrict__ hist,
                                                     const unsigned* __restrict__ B2,
                                                     unsigned* __restrict__ ebuf) {
    __shared__ unsigned lcur[NBINS];
    for (int i = threadIdx.x; i < NBINS; i += BTHREADS)
        lcur[i] = B2[i] + hist[i * BINBLK + blockIdx.x];
    __syncthreads();
    const int4* s4 = (const int4*)src;
    const int4* d4 = (const int4*)dst;
    const int base = blockIdx.x * CHUNK4;
    for (int i = threadIdx.x; i < CHUNK4; i += BTHREADS) {
        int4 sv = s4[base + i];
        int4 dv = d4[base + i];
        unsigned p;
        p = atomicAdd(&lcur[(dv.x >> BKT_SHIFT) * NTILE + (unsigned)sv.x / TILE_SZ], 1u);
        ebuf[p] = ((unsigned)(dv.x & 127) << 17) | (unsigned)sv.x;
        p = atomicAdd(&lcur[(dv.y >> BKT_SHIFT) * NTILE + (unsigned)sv.y / TILE_SZ], 1u);
        ebuf[p] = ((unsigned)(dv.y & 127) << 17) | (unsigned)sv.y;
        p = atomicAdd(&lcur[(dv.z >> BKT_SHIFT) * NTILE + (unsigned)sv.z / TILE_SZ], 1u);
        ebuf[p] = ((unsigned)(dv.z & 127) << 17) | (unsigned)sv.z;
        p = atomicAdd(&lcur[(dv.w >> BKT_SHIFT) * NTILE + (unsigned)sv.w / TILE_SZ], 1u);
        ebuf[p] = ((unsigned)(dv.w & 127) << 17) | (unsigned)sv.w;
    }
}

// pass 5: one block per bucket -> degree, rowptr, dis, tile-ordered csr fill
__global__ __launch_bounds__(BTHREADS) void k_fill5(const unsigned* __restrict__ ebuf,
                                                    const unsigned* __restrict__ B2,
                                                    unsigned* __restrict__ rowptr,
                                                    float* __restrict__ dis,
                                                    int* __restrict__ csr, int N, int E) {
    __shared__ unsigned lcnt[128];
    __shared__ unsigned lcur[128];
    const int b = blockIdx.x, t = threadIdx.x;
    const int n0 = b << BKT_SHIFT;
    const int cnt = min(128, N - n0);
    if (t < 128) lcnt[t] = 0;
    __syncthreads();
    const unsigned beg = B2[b * NTILE], end = B2[b * NTILE + NTILE];
    for (unsigned i = beg + t; i < end; i += BTHREADS)
        atomicAdd(&lcnt[ebuf[i] >> 17], 1u);
    __syncthreads();
    unsigned deg_t = (t < 128) ? lcnt[t] : 0u;
    if (t < 128) lcur[t] = deg_t;
    __syncthreads();
    for (int off = 1; off < 128; off <<= 1) {
        unsigned x = 0;
        if (t < 128) {
            x = lcur[t];
            if (t >= off) x += lcur[t - off];
        }
        __syncthreads();
        if (t < 128) lcur[t] = x;
        __syncthreads();
    }
    if (t < cnt) {
        unsigned ex = beg + lcur[t] - deg_t;   // global exclusive offset
        rowptr[n0 + t] = ex;
        dis[n0 + t] = rsqrtf((float)(deg_t + 1u));
        lcur[t] = ex;                           // becomes fill cursor
    }
    if (b == (int)gridDim.x - 1 && t == 0) rowptr[N] = (unsigned)E;
    __syncthreads();
    for (unsigned i = beg + t; i < end; i += BTHREADS) {
        unsigned v = ebuf[i];
        unsigned pos = atomicAdd(&lcur[v >> 17], 1u);
        csr[pos] = (int)(v & 0x1FFFFu);
    }
}

// ---------------- bf16 MFMA GEMM: C[M,128] = dis[row] * (A[M,K] @ Wt^T), C bf16 ----------------
template<bool AF32>
__global__ __launch_bounds__(256) void k_gemm_mfma(const void* __restrict__ Ap,
                                                   const unsigned short* __restrict__ Wt,  // [128][K] bf16
                                                   const float* __restrict__ dis,
                                                   unsigned short* __restrict__ C,
                                                   int M, int K) {
    __shared__ unsigned short As[128][40];   // [row][k] pad 40 (80B stride: 2-way free)
    __shared__ unsigned short Bs[128][40];   // [col][k]
    const int tid = threadIdx.x;
    const int w = tid >> 6;
    const int l = tid & 63;
    const int row0 = blockIdx.x * 128;

    f32x4 acc[2][8];
#pragma unroll
    for (int i = 0; i < 2; i++)
#pragma unroll
        for (int f = 0; f < 8; f++) acc[i][f] = (f32x4){0.f, 0.f, 0.f, 0.f};

    for (int k0 = 0; k0 < K; k0 += 32) {
#pragma unroll
        for (int t = 0; t < 2; t++) {
            int g = tid + t * 256;           // 512 groups of 8 elems
            int r = g >> 2, k8 = (g & 3) * 8;
            int ar = row0 + r;
            u16x8 u = {0, 0, 0, 0, 0, 0, 0, 0};
            if (AF32) {
                if (ar < M) {
                    const float* ap = (const float*)Ap + (size_t)ar * K + k0 + k8;
                    float4 v0 = *(const float4*)ap;
                    float4 v1 = *(const float4*)(ap + 4);
                    u[0] = f2bf(v0.x); u[1] = f2bf(v0.y); u[2] = f2bf(v0.z); u[3] = f2bf(v0.w);
                    u[4] = f2bf(v1.x); u[5] = f2bf(v1.y); u[6] = f2bf(v1.z); u[7] = f2bf(v1.w);
                }
            } else {
                if (ar < M)
                    u = *(const u16x8*)((const unsigned short*)Ap + (size_t)ar * K + k0 + k8);
            }
            *(u16x8*)&As[r][k8] = u;
        }
#pragma unroll
        for (int t = 0; t < 2; t++) {
            int g = tid + t * 256;
            int n = g >> 2, k8 = (g & 3) * 8;
            *(u16x8*)&Bs[n][k8] = *(const u16x8*)&Wt[(size_t)n * K + k0 + k8];
        }
        __syncthreads();

        bf16x8 a0 = *(const bf16x8*)&As[w * 32 + (l & 15)][(l >> 4) * 8];
        bf16x8 a1 = *(const bf16x8*)&As[w * 32 + 16 + (l & 15)][(l >> 4) * 8];
#pragma unroll
        for (int f = 0; f < 8; f++) {
            bf16x8 bfr = *(const bf16x8*)&Bs[f * 16 + (l & 15)][(l >> 4) * 8];
            acc[0][f] = __builtin_amdgcn_mfma_f32_16x16x32_bf16(a0, bfr, acc[0][f], 0, 0, 0);
            acc[1][f] = __builtin_amdgcn_mfma_f32_16x16x32_bf16(a1, bfr, acc[1][f], 0, 0, 0);
        }
        __syncthreads();
    }

    const int colb = l & 15;
    const int rowq = (l >> 4) * 4;
#pragma unroll
    for (int i = 0; i < 2; i++)
#pragma unroll
        for (int r = 0; r < 4; r++) {
            int row = row0 + w * 32 + i * 16 + rowq + r;
            if (row < M) {
                float dv = dis[row];
#pragma unroll
                for (int f = 0; f < 8; f++)
                    C[(size_t)row * 128 + f * 16 + colb] = f2bf(dv * acc[i][f][r]);
            }
        }
}

// ---------------- aggregate: wave per dst node, pre-scaled bf16 gather, unrolled x8 ----------------
// h rows are hs = dis[s]*h_raw[s]; out[d] = dis[d]*(sum_e hs[s_e] + hs[d]) + bias
template<int RELU, int OUTBF>
__global__ __launch_bounds__(256) void k_aggregate(const unsigned short* __restrict__ h,
                                                   const int* __restrict__ csr_src,
                                                   const unsigned* __restrict__ rowptr,
                                                   const float* __restrict__ dis,
                                                   const float* __restrict__ bias,
                                                   void* __restrict__ outp, int N) {
    const int wid = (int)((blockIdx.x * (blockDim.x >> 6)) + (threadIdx.x >> 6));
    const int d = __builtin_amdgcn_readfirstlane(wid);   // wave-uniform -> SGPR
    if (d >= N) return;
    const int lane = threadIdx.x & 63;
    const unsigned beg = rowptr[d], end = rowptr[d + 1];
    const float dd = dis[d];
    const unsigned* h1 = reinterpret_cast<const unsigned*>(h);  // 64 dwords/row = 2 bf16 each

    unsigned hv = h1[(size_t)d * 64 + lane];
    float ax = __uint_as_float(hv << 16);           // self term (pre-scaled)
    float ay = __uint_as_float(hv & 0xffff0000u);

    unsigned e = beg;
    for (; e + 8 <= end; e += 8) {
        int s[8];
        unsigned v[8];
#pragma unroll
        for (int u = 0; u < 8; u++) s[u] = csr_src[e + u];
#pragma unroll
        for (int u = 0; u < 8; u++) v[u] = h1[(size_t)s[u] * 64 + lane];
#pragma unroll
        for (int u = 0; u < 8; u++) {
            ax += __uint_as_float(v[u] << 16);
            ay += __uint_as_float(v[u] & 0xffff0000u);
        }
    }
    for (; e < end; e++) {
        int s0 = csr_src[e];
        unsigned v0 = h1[(size_t)s0 * 64 + lane];
        ax += __uint_as_float(v0 << 16);
        ay += __uint_as_float(v0 & 0xffff0000u);
    }
    float2 bv = reinterpret_cast<const float2*>(bias)[lane];
    float r0 = fmaf(dd, ax, bv.x);
    float r1 = fmaf(dd, ay, bv.y);
    if (RELU) { r0 = fmaxf(r0, 0.f); r1 = fmaxf(r1, 0.f); }
    if (OUTBF) {
        unsigned pack = (unsigned)f2bf(r0) | ((unsigned)f2bf(r1) << 16);
        reinterpret_cast<unsigned*>(outp)[(size_t)d * 64 + lane] = pack;
    } else {
        reinterpret_cast<float2*>(outp)[(size_t)d * 64 + lane] = make_float2(r0, r1);
    }
}

extern "C" void kernel_launch(void* const* d_in, const int* in_sizes, int n_in,
                              void* d_out, int out_size, void* d_ws, size_t ws_size,
                              hipStream_t stream) {
    const float* x  = (const float*)d_in[0];
    const int*   ei = (const int*)d_in[1];
    const float* W1 = (const float*)d_in[2];
    const float* b1 = (const float*)d_in[3];
    const float* W2 = (const float*)d_in[4];
    const float* b2 = (const float*)d_in[5];
    const int* src = ei;             // edge_index[0]
    const int* dst = ei + N_EDGES;   // edge_index[1]
    float* out = (float*)d_out;

    char* ws = (char*)d_ws;
    float*          dis    = (float*)ws;                             // 400128
    unsigned*       rowptr = (unsigned*)(ws + 400128);               // 400128
    unsigned*       B2     = (unsigned*)(ws + 800256);               // 25088
    unsigned*       bintot = (unsigned*)(ws + 825344);               // 25088
    unsigned short* wt1    = (unsigned short*)(ws + 850688);         // 98304
    unsigned short* wt2    = (unsigned short*)(ws + 948992);         // 32768
    unsigned*       hist   = (unsigned*)(ws + 981760);               // NBINS*BINBLK*4 = 6406144
    unsigned*       ebuf   = (unsigned*)(ws + 7387904);              // 12.8 MB
    int*            csr    = (int*)(ws + 20187904);                  // 12.8 MB
    unsigned short* hbf    = (unsigned short*)(ws + 32987904);       // 25.6 MB
    unsigned short* abf    = (unsigned short*)(ws + 58587904);       // 25.6 MB

    // ---- weight conversion ----
    k_wt2<<<((IN_CH + HID) * 128 + 255) / 256, 256, 0, stream>>>(W1, W2, wt1, wt2);

    // ---- edge binning into (dst-bucket x src-tile) cells + CSR/rowptr/dis ----
    k_bhist2<<<BINBLK, BTHREADS, 0, stream>>>(src, dst, hist);
    k_bscan<<<NBINS, BINBLK, 0, stream>>>(hist, bintot);
    k_gs<<<1, 1024, 0, stream>>>(bintot, B2, NBINS, N_EDGES);
    k_bscat2<<<BINBLK, BTHREADS, 0, stream>>>(src, dst, hist, B2, ebuf);
    k_fill5<<<NBKT, BTHREADS, 0, stream>>>(ebuf, B2, rowptr, dis, csr, N_NODES, N_EDGES);

    // ---- layer 1 ----
    k_gemm_mfma<true><<<(N_NODES + 127) / 128, 256, 0, stream>>>(x, wt1, dis, hbf, N_NODES, IN_CH);
    k_aggregate<1, 1><<<(N_NODES * 64 + 255) / 256, 256, 0, stream>>>(hbf, csr, rowptr, dis, b1, abf, N_NODES);

    // ---- layer 2 ----
    k_gemm_mfma<false><<<(N_NODES + 127) / 128, 256, 0, stream>>>(abf, wt2, dis, hbf, N_NODES, HID);
    k_aggregate<0, 0><<<(N_NODES * 64 + 255) / 256, 256, 0, stream>>>(hbf, csr, rowptr, dis, b2, out, N_NODES);
}

// Round 13
// 381.718 us; speedup vs baseline: 1.0691x; 1.0691x over previous
//
#include <hip/hip_runtime.h>

#define N_NODES 100000
#define N_EDGES 3200000
#define IN_CH   384
#define HID     128
#define BKT_SHIFT 7
#define NBKT ((N_NODES + 127) >> 7)      // 782 buckets x 128 dst nodes
#define BINBLK 256                       // blocks in binning passes (full chip)
#define BTHREADS 512
#define CHUNK4 (N_EDGES / 4 / BINBLK)    // 3125 int4 per block (exact)

typedef __attribute__((ext_vector_type(8))) short          bf16x8;
typedef __attribute__((ext_vector_type(8))) unsigned short u16x8;
typedef __attribute__((ext_vector_type(4))) float          f32x4;

static __device__ __forceinline__ unsigned short f2bf(float f) {
    unsigned u = __float_as_uint(f);
    unsigned r = (u + 0x7fffu + ((u >> 16) & 1u)) >> 16;   // RTN-even
    return (unsigned short)r;
}

// ---------------- both W -> transposed bf16: Wt[n][k] ----------------
__global__ void k_wt2(const float* __restrict__ W1, const float* __restrict__ W2,
                      unsigned short* __restrict__ wt1, unsigned short* __restrict__ wt2) {
    int i = blockIdx.x * blockDim.x + threadIdx.x;
    if (i < IN_CH * 128) {
        int k = i >> 7, n = i & 127;
        wt1[(size_t)n * IN_CH + k] = f2bf(W1[i]);
    } else if (i < (IN_CH + HID) * 128) {
        int j = i - IN_CH * 128;
        int k = j >> 7, n = j & 127;
        wt2[(size_t)n * HID + k] = f2bf(W2[j]);
    }
}

// ---------------- pass 1: per-block LDS histogram over 782 buckets (dst only) ----------------
__global__ __launch_bounds__(BTHREADS) void k_bhist(const int* __restrict__ dst,
                                                    unsigned* __restrict__ hist) {
    __shared__ unsigned lh[NBKT];
    for (int i = threadIdx.x; i < NBKT; i += BTHREADS) lh[i] = 0;
    __syncthreads();
    const int4* d4 = (const int4*)dst;
    const int base = blockIdx.x * CHUNK4;
    for (int i = threadIdx.x; i < CHUNK4; i += BTHREADS) {
        int4 v = d4[base + i];
        atomicAdd(&lh[v.x >> BKT_SHIFT], 1u);
        atomicAdd(&lh[v.y >> BKT_SHIFT], 1u);
        atomicAdd(&lh[v.z >> BKT_SHIFT], 1u);
        atomicAdd(&lh[v.w >> BKT_SHIFT], 1u);
    }
    __syncthreads();
    for (int i = threadIdx.x; i < NBKT; i += BTHREADS) hist[i * BINBLK + blockIdx.x] = lh[i];
}

// pass 2: per-bucket exclusive scan over BINBLK block counts; emit bucket totals
__global__ __launch_bounds__(BINBLK) void k_bscan(unsigned* __restrict__ hist,
                                                  unsigned* __restrict__ bintot) {
    __shared__ unsigned s[BINBLK];
    const int b = blockIdx.x, t = threadIdx.x;
    unsigned v = hist[b * BINBLK + t];
    s[t] = v;
    __syncthreads();
    for (int off = 1; off < BINBLK; off <<= 1) {
        unsigned x = s[t];
        unsigned y = (t >= off) ? s[t - off] : 0u;
        __syncthreads();
        s[t] = x + y;
        __syncthreads();
    }
    hist[b * BINBLK + t] = s[t] - v;          // exclusive within bucket
    if (t == BINBLK - 1) bintot[b] = s[BINBLK - 1];
}

// pass 3: single-block exclusive scan of NBKT bucket totals -> B2; B2[NBKT] = E
__global__ __launch_bounds__(1024) void k_gs(const unsigned* __restrict__ bintot,
                                             unsigned* __restrict__ B2, int n, int E) {
    __shared__ unsigned s[1024];
    const int t = threadIdx.x;
    unsigned v = (t < n) ? bintot[t] : 0u;
    s[t] = v;
    __syncthreads();
    for (int off = 1; off < 1024; off <<= 1) {
        unsigned x = s[t];
        unsigned y = (t >= off) ? s[t - off] : 0u;
        __syncthreads();
        s[t] = x + y;
        __syncthreads();
    }
    if (t < n) B2[t] = s[t] - v;
    if (t == 0) B2[n] = (unsigned)E;
}

// pass 4: scatter packed (loc7|src17) into bucket-grouped ebuf; one 64B line per (block,bucket)
__global__ __launch_bounds__(BTHREADS) void k_bscat(const int* __restrict__ src,
                                                    const int* __restrict__ dst,
                                                    const unsigned* __restrict__ hist,
                                                    const unsigned* __restrict__ B2,
                                                    unsigned* __restrict__ ebuf) {
    __shared__ unsigned lcur[NBKT];
    for (int i = threadIdx.x; i < NBKT; i += BTHREADS)
        lcur[i] = B2[i] + hist[i * BINBLK + blockIdx.x];
    __syncthreads();
    const int4* s4 = (const int4*)src;
    const int4* d4 = (const int4*)dst;
    const int base = blockIdx.x * CHUNK4;
    for (int i = threadIdx.x; i < CHUNK4; i += BTHREADS) {
        int4 sv = s4[base + i];
        int4 dv = d4[base + i];
        unsigned p;
        p = atomicAdd(&lcur[dv.x >> BKT_SHIFT], 1u);
        ebuf[p] = ((unsigned)(dv.x & 127) << 17) | (unsigned)sv.x;
        p = atomicAdd(&lcur[dv.y >> BKT_SHIFT], 1u);
        ebuf[p] = ((unsigned)(dv.y & 127) << 17) | (unsigned)sv.y;
        p = atomicAdd(&lcur[dv.z >> BKT_SHIFT], 1u);
        ebuf[p] = ((unsigned)(dv.z & 127) << 17) | (unsigned)sv.z;
        p = atomicAdd(&lcur[dv.w >> BKT_SHIFT], 1u);
        ebuf[p] = ((unsigned)(dv.w & 127) << 17) | (unsigned)sv.w;
    }
}

// pass 5: one block per bucket -> degree, rowptr, dis, csr fill
__global__ __launch_bounds__(BTHREADS) void k_fill(const unsigned* __restrict__ ebuf,
                                                   const unsigned* __restrict__ B2,
                                                   unsigned* __restrict__ rowptr,
                                                   float* __restrict__ dis,
                                                   int* __restrict__ csr, int N, int E) {
    __shared__ unsigned lcnt[128];
    __shared__ unsigned lcur[128];
    const int b = blockIdx.x, t = threadIdx.x;
    const int n0 = b << BKT_SHIFT;
    const int cnt = min(128, N - n0);
    if (t < 128) lcnt[t] = 0;
    __syncthreads();
    const unsigned beg = B2[b], end = B2[b + 1];
    for (unsigned i = beg + t; i < end; i += BTHREADS)
        atomicAdd(&lcnt[ebuf[i] >> 17], 1u);
    __syncthreads();
    unsigned deg_t = (t < 128) ? lcnt[t] : 0u;
    if (t < 128) lcur[t] = deg_t;
    __syncthreads();
    for (int off = 1; off < 128; off <<= 1) {
        unsigned x = 0;
        if (t < 128) {
            x = lcur[t];
            if (t >= off) x += lcur[t - off];
        }
        __syncthreads();
        if (t < 128) lcur[t] = x;
        __syncthreads();
    }
    if (t < cnt) {
        unsigned ex = beg + lcur[t] - deg_t;   // global exclusive offset
        rowptr[n0 + t] = ex;
        dis[n0 + t] = rsqrtf((float)(deg_t + 1u));
        lcur[t] = ex;                           // becomes fill cursor
    }
    if (b == (int)gridDim.x - 1 && t == 0) rowptr[N] = (unsigned)E;
    __syncthreads();
    for (unsigned i = beg + t; i < end; i += BTHREADS) {
        unsigned v = ebuf[i];
        unsigned pos = atomicAdd(&lcur[v >> 17], 1u);
        csr[pos] = (int)(v & 0x1FFFFu);
    }
}

// ---------------- bf16 MFMA GEMM: C[M,128] = dis[row] * (A[M,K] @ Wt^T), C bf16 ----------------
template<bool AF32>
__global__ __launch_bounds__(256) void k_gemm_mfma(const void* __restrict__ Ap,
                                                   const unsigned short* __restrict__ Wt,  // [128][K] bf16
                                                   const float* __restrict__ dis,
                                                   unsigned short* __restrict__ C,
                                                   int M, int K) {
    __shared__ unsigned short As[128][40];   // [row][k] pad 40 (80B stride: 2-way free)
    __shared__ unsigned short Bs[128][40];   // [col][k]
    const int tid = threadIdx.x;
    const int w = tid >> 6;
    const int l = tid & 63;
    const int row0 = blockIdx.x * 128;

    f32x4 acc[2][8];
#pragma unroll
    for (int i = 0; i < 2; i++)
#pragma unroll
        for (int f = 0; f < 8; f++) acc[i][f] = (f32x4){0.f, 0.f, 0.f, 0.f};

    for (int k0 = 0; k0 < K; k0 += 32) {
#pragma unroll
        for (int t = 0; t < 2; t++) {
            int g = tid + t * 256;           // 512 groups of 8 elems
            int r = g >> 2, k8 = (g & 3) * 8;
            int ar = row0 + r;
            u16x8 u = {0, 0, 0, 0, 0, 0, 0, 0};
            if (AF32) {
                if (ar < M) {
                    const float* ap = (const float*)Ap + (size_t)ar * K + k0 + k8;
                    float4 v0 = *(const float4*)ap;
                    float4 v1 = *(const float4*)(ap + 4);
                    u[0] = f2bf(v0.x); u[1] = f2bf(v0.y); u[2] = f2bf(v0.z); u[3] = f2bf(v0.w);
                    u[4] = f2bf(v1.x); u[5] = f2bf(v1.y); u[6] = f2bf(v1.z); u[7] = f2bf(v1.w);
                }
            } else {
                if (ar < M)
                    u = *(const u16x8*)((const unsigned short*)Ap + (size_t)ar * K + k0 + k8);
            }
            *(u16x8*)&As[r][k8] = u;
        }
#pragma unroll
        for (int t = 0; t < 2; t++) {
            int g = tid + t * 256;
            int n = g >> 2, k8 = (g & 3) * 8;
            *(u16x8*)&Bs[n][k8] = *(const u16x8*)&Wt[(size_t)n * K + k0 + k8];
        }
        __syncthreads();

        bf16x8 a0 = *(const bf16x8*)&As[w * 32 + (l & 15)][(l >> 4) * 8];
        bf16x8 a1 = *(const bf16x8*)&As[w * 32 + 16 + (l & 15)][(l >> 4) * 8];
#pragma unroll
        for (int f = 0; f < 8; f++) {
            bf16x8 bfr = *(const bf16x8*)&Bs[f * 16 + (l & 15)][(l >> 4) * 8];
            acc[0][f] = __builtin_amdgcn_mfma_f32_16x16x32_bf16(a0, bfr, acc[0][f], 0, 0, 0);
            acc[1][f] = __builtin_amdgcn_mfma_f32_16x16x32_bf16(a1, bfr, acc[1][f], 0, 0, 0);
        }
        __syncthreads();
    }

    const int colb = l & 15;
    const int rowq = (l >> 4) * 4;
#pragma unroll
    for (int i = 0; i < 2; i++)
#pragma unroll
        for (int r = 0; r < 4; r++) {
            int row = row0 + w * 32 + i * 16 + rowq + r;
            if (row < M) {
                float dv = dis[row];
#pragma unroll
                for (int f = 0; f < 8; f++)
                    C[(size_t)row * 128 + f * 16 + colb] = f2bf(dv * acc[i][f][r]);
            }
        }
}

// ---------------- aggregate: wave per dst node, pre-scaled bf16 gather, unrolled x8 ----------------
// h rows are hs = dis[s]*h_raw[s]; out[d] = dis[d]*(sum_e hs[s_e] + hs[d]) + bias
template<int RELU, int OUTBF>
__global__ __launch_bounds__(256) void k_aggregate(const unsigned short* __restrict__ h,
                                                   const int* __restrict__ csr_src,
                                                   const unsigned* __restrict__ rowptr,
                                                   const float* __restrict__ dis,
                                                   const float* __restrict__ bias,
                                                   void* __restrict__ outp, int N) {
    const int wid = (int)((blockIdx.x * (blockDim.x >> 6)) + (threadIdx.x >> 6));
    const int d = __builtin_amdgcn_readfirstlane(wid);   // wave-uniform -> SGPR
    if (d >= N) return;
    const int lane = threadIdx.x & 63;
    const unsigned beg = rowptr[d], end = rowptr[d + 1];
    const float dd = dis[d];
    const unsigned* h1 = reinterpret_cast<const unsigned*>(h);  // 64 dwords/row = 2 bf16 each

    unsigned hv = h1[(size_t)d * 64 + lane];
    float ax = __uint_as_float(hv << 16);           // self term (pre-scaled)
    float ay = __uint_as_float(hv & 0xffff0000u);

    unsigned e = beg;
    for (; e + 8 <= end; e += 8) {
        int s[8];
        unsigned v[8];
#pragma unroll
        for (int u = 0; u < 8; u++) s[u] = csr_src[e + u];
#pragma unroll
        for (int u = 0; u < 8; u++) v[u] = h1[(size_t)s[u] * 64 + lane];
#pragma unroll
        for (int u = 0; u < 8; u++) {
            ax += __uint_as_float(v[u] << 16);
            ay += __uint_as_float(v[u] & 0xffff0000u);
        }
    }
    for (; e < end; e++) {
        int s0 = csr_src[e];
        unsigned v0 = h1[(size_t)s0 * 64 + lane];
        ax += __uint_as_float(v0 << 16);
        ay += __uint_as_float(v0 & 0xffff0000u);
    }
    float2 bv = reinterpret_cast<const float2*>(bias)[lane];
    float r0 = fmaf(dd, ax, bv.x);
    float r1 = fmaf(dd, ay, bv.y);
    if (RELU) { r0 = fmaxf(r0, 0.f); r1 = fmaxf(r1, 0.f); }
    if (OUTBF) {
        unsigned pack = (unsigned)f2bf(r0) | ((unsigned)f2bf(r1) << 16);
        reinterpret_cast<unsigned*>(outp)[(size_t)d * 64 + lane] = pack;
    } else {
        reinterpret_cast<float2*>(outp)[(size_t)d * 64 + lane] = make_float2(r0, r1);
    }
}

extern "C" void kernel_launch(void* const* d_in, const int* in_sizes, int n_in,
                              void* d_out, int out_size, void* d_ws, size_t ws_size,
                              hipStream_t stream) {
    const float* x  = (const float*)d_in[0];
    const int*   ei = (const int*)d_in[1];
    const float* W1 = (const float*)d_in[2];
    const float* b1 = (const float*)d_in[3];
    const float* W2 = (const float*)d_in[4];
    const float* b2 = (const float*)d_in[5];
    const int* src = ei;             // edge_index[0]
    const int* dst = ei + N_EDGES;   // edge_index[1]
    float* out = (float*)d_out;

    char* ws = (char*)d_ws;
    float*          dis    = (float*)ws;                             // 400128
    unsigned*       rowptr = (unsigned*)(ws + 400128);               // 400128
    unsigned*       B2     = (unsigned*)(ws + 800256);               // 3200 (NBKT+1 u32, pad)
    unsigned*       bintot = (unsigned*)(ws + 803584);               // 3200
    unsigned short* wt1    = (unsigned short*)(ws + 806912);         // 98304
    unsigned short* wt2    = (unsigned short*)(ws + 905216);         // 32768
    unsigned*       hist   = (unsigned*)(ws + 937984);               // NBKT*BINBLK*4 = 800768
    unsigned*       ebuf   = (unsigned*)(ws + 1738880);              // 12.8 MB
    int*            csr    = (int*)(ws + 14538880);                  // 12.8 MB
    unsigned short* hbf    = (unsigned short*)(ws + 27338880);       // 25.6 MB
    unsigned short* abf    = (unsigned short*)(ws + 52938880);       // 25.6 MB

    // ---- weight conversion ----
    k_wt2<<<((IN_CH + HID) * 128 + 255) / 256, 256, 0, stream>>>(W1, W2, wt1, wt2);

    // ---- CSR build: bucket counting sort (one 64B line per block-bucket cell) ----
    k_bhist<<<BINBLK, BTHREADS, 0, stream>>>(dst, hist);
    k_bscan<<<NBKT, BINBLK, 0, stream>>>(hist, bintot);
    k_gs<<<1, 1024, 0, stream>>>(bintot, B2, NBKT, N_EDGES);
    k_bscat<<<BINBLK, BTHREADS, 0, stream>>>(src, dst, hist, B2, ebuf);
    k_fill<<<NBKT, BTHREADS, 0, stream>>>(ebuf, B2, rowptr, dis, csr, N_NODES, N_EDGES);

    // ---- layer 1 ----
    k_gemm_mfma<true><<<(N_NODES + 127) / 128, 256, 0, stream>>>(x, wt1, dis, hbf, N_NODES, IN_CH);
    k_aggregate<1, 1><<<(N_NODES * 64 + 255) / 256, 256, 0, stream>>>(hbf, csr, rowptr, dis, b1, abf, N_NODES);

    // ---- layer 2 ----
    k_gemm_mfma<false><<<(N_NODES + 127) / 128, 256, 0, stream>>>(abf, wt2, dis, hbf, N_NODES, HID);
    k_aggregate<0, 0><<<(N_NODES * 64 + 255) / 256, 256, 0, stream>>>(hbf, csr, rowptr, dis, b2, out, N_NODES);
}